// Round 1
// 372.140 us; speedup vs baseline: 1.0550x; 1.0550x over previous
//
#include <hip/hip_runtime.h>
#include <math.h>

#define B_SZ    16384
#define NNZ_PER 32
#define NNZ     (B_SZ * NNZ_PER)
#define FT_OUT  512
#define F_BIG   49152
#define F_SMALL 768
#define MODV    640

// prep grid partition
#define TP_A     1536              // W_ft tiles: 768 c-tiles(64) x 2 o-tiles(256)
#define TP_B     80                // W_fft 64x64 tiles: 8 ot x 10 ct
#define HISTB    512
#define PREP_GRID (TP_A + TP_B + HISTB)

#define ROWS_PER_BLOCK 4           // main: 256 threads = 4 waves, 1 row/wave

// ---------------------------------------------------------------------------
// ws layout:
//   Wt_bf   : F_BIG*FT_OUT ushort      48 MB  transposed big weight, bf16
//   Wfft_t  : MODV*FT_OUT float        1.3 MB transposed small weight (fp32)
//   H       : 2*MODV*MODV float        3.3 MB weighted histograms
// (fft_acc removed — fft contraction folded into main_kernel)
// ---------------------------------------------------------------------------

__device__ __forceinline__ unsigned short f32_to_bf16_rne(float f) {
    union { float f; unsigned int u; } v; v.f = f;
    unsigned int u = v.u;
    return (unsigned short)((u + 0x7fffu + ((u >> 16) & 1u)) >> 16);
}

__device__ __forceinline__ void unpack_bf16x2(unsigned int u, float& lo, float& hi) {
    union { unsigned int i; float f; } a, b;
    a.i = u << 16;            // even element
    b.i = u & 0xffff0000u;    // odd element
    lo = a.f; hi = b.f;
}

__device__ __forceinline__ float clip01(float x) {
    return fminf(fmaxf(x, 0.0f), 1.0f);
}

// accumulate one bf16x8 weight row chunk into 8 fp32 accumulators
__device__ __forceinline__ void acc8(uint4 w, float v, float* a) {
    float e0, e1;
    unpack_bf16x2(w.x, e0, e1); a[0] += v * e0; a[1] += v * e1;
    unpack_bf16x2(w.y, e0, e1); a[2] += v * e0; a[3] += v * e1;
    unpack_bf16x2(w.z, e0, e1); a[4] += v * e0; a[5] += v * e1;
    unpack_bf16x2(w.w, e0, e1); a[6] += v * e0; a[7] += v * e1;
}

// a[0..7] += h * (x.xyzw, y.xyzw)
__device__ __forceinline__ void fma8(float h, float4 x, float4 y, float* a) {
    a[0] += h * x.x; a[1] += h * x.y; a[2] += h * x.z; a[3] += h * x.w;
    a[4] += h * y.x; a[5] += h * y.y; a[6] += h * y.z; a[7] += h * y.w;
}

// Fused prologue: transpose+bf16-quantize W_ft, transpose W_fft, histogram.
// All stores CACHED (not nontemporal): Wt/Wfft_t are re-read by later kernels,
// NT in R6 evicted them from L3 and cost main ~5% (R2 vs R6 evidence).
__global__ __launch_bounds__(256)
void prep_kernel(const float* __restrict__ W_ft, const float* __restrict__ W_fft,
                 const int* __restrict__ stm, const int* __restrict__ nstm,
                 const float* __restrict__ vals,
                 unsigned short* __restrict__ Wt, float* __restrict__ Wfft_t,
                 float* __restrict__ H) {
    __shared__ __align__(16) unsigned char smem[256 * 68 * 2];   // 34.8 KB
    int b = blockIdx.x;
    int tid = threadIdx.x;
    if (b < TP_A) {
        // ---- W_ft transpose: tile c0..c0+63, o0..o0+255; LDS bf16 tA[o][c] ----
        unsigned short (*tA)[68] = (unsigned short (*)[68])smem;
        int ct = b >> 1, ot = b & 1;
        int c0 = ct * 64, o0 = ot * 256;
        int orow = tid >> 4, c4 = (tid & 15) * 4;
#pragma unroll
        for (int it = 0; it < 16; it++) {
            int oo = orow + it * 16;
            float4 f = *(const float4*)(W_ft + (size_t)(o0 + oo) * F_BIG + c0 + c4);
            tA[oo][c4 + 0] = f32_to_bf16_rne(f.x);
            tA[oo][c4 + 1] = f32_to_bf16_rne(f.y);
            tA[oo][c4 + 2] = f32_to_bf16_rne(f.z);
            tA[oo][c4 + 3] = f32_to_bf16_rne(f.w);
        }
        __syncthreads();
        // store v2: lane = column cc (stride-1 u16 LDS reads, conflict-free);
        // each lane emits 128 B contiguous (64 o) of its Wt row.
        int cc = tid & 63, och = tid >> 6;      // och 0..3
        int obase = och * 64;
        unsigned short* dst = Wt + (size_t)(c0 + cc) * FT_OUT + o0 + obase;
#pragma unroll
        for (int k = 0; k < 8; k++) {
            int o8 = obase + k * 8;
            uint4 pk;
            pk.x = (unsigned int)tA[o8 + 0][cc] | ((unsigned int)tA[o8 + 1][cc] << 16);
            pk.y = (unsigned int)tA[o8 + 2][cc] | ((unsigned int)tA[o8 + 3][cc] << 16);
            pk.z = (unsigned int)tA[o8 + 4][cc] | ((unsigned int)tA[o8 + 5][cc] << 16);
            pk.w = (unsigned int)tA[o8 + 6][cc] | ((unsigned int)tA[o8 + 7][cc] << 16);
            *(uint4*)(dst + k * 8) = pk;
        }
    } else if (b < TP_A + TP_B) {
        // ---- W_fft transpose: 64x64 fp32 tiles ----
        float (*tB)[65] = (float (*)[65])smem;
        int b2 = b - TP_A;
        int nct = MODV / 64;
        int ot = b2 / nct, ct = b2 % nct;
        int c0 = ct * 64, o0 = ot * 64;
        int rr = tid >> 4, c4 = (tid & 15) * 4;
#pragma unroll
        for (int it = 0; it < 4; it++) {
            int oo = rr + it * 16;
            float4 f = *(const float4*)(W_fft + (size_t)(o0 + oo) * F_SMALL + c0 + c4);
            tB[oo][c4 + 0] = f.x; tB[oo][c4 + 1] = f.y;
            tB[oo][c4 + 2] = f.z; tB[oo][c4 + 3] = f.w;
        }
        __syncthreads();
#pragma unroll
        for (int it = 0; it < 4; it++) {
            int idx = tid + it * 256;
            int cc = idx >> 4, g = idx & 15;
            float4 v = make_float4(tB[g * 4 + 0][cc], tB[g * 4 + 1][cc],
                                   tB[g * 4 + 2][cc], tB[g * 4 + 3][cc]);
            *(float4*)(Wfft_t + (size_t)(c0 + cc) * FT_OUT + o0 + g * 4) = v;
        }
    } else {
        // ---- mod-640 weighted histogram ----
        int i0 = (b - TP_A - TP_B) * 256 + tid;
        for (int e = i0; e < 2 * NNZ; e += HISTB * 256) {
            int side = (e >= NNZ) ? 1 : 0;
            int j = e - side * NNZ;
            const int* arr = side ? nstm : stm;
            int r = arr[j] % MODV;          // row indices at offset 0
            int c = arr[NNZ + j] % MODV;    // col indices at offset NNZ
            atomicAdd(&H[(size_t)side * MODV * MODV + r * MODV + c], vals[j]);
        }
    }
}

// 4 rows per block (4 waves, 1 row/wave). Explicit next-k gather prefetch.
// Rows < MODV additionally fold in the H @ Wfft^T contraction (replaces the
// former fft_gemm kernel): extra ~8 us VALU on 160 "fat" blocks, dispatched
// first, absorbed under the memory-bound gather schedule.
__global__ __launch_bounds__(256)
void main_kernel(const int* __restrict__ stm, const int* __restrict__ nstm,
                 const float* __restrict__ vals,
                 const unsigned short* __restrict__ Wt,
                 const float* __restrict__ b_ft, const float* __restrict__ b_fft,
                 const float* __restrict__ H, const float* __restrict__ Wfft_t,
                 const float* __restrict__ W_out, const float* __restrict__ b_out,
                 float* __restrict__ out) {
    __shared__ int   s_c[ROWS_PER_BLOCK][2][NNZ_PER];
    __shared__ float s_v[ROWS_PER_BLOCK][NNZ_PER];

    int tid  = threadIdx.x;
    int row0 = blockIdx.x * ROWS_PER_BLOCK;

    {
        int r = tid >> 5;            // 0..7
        int k = tid & 31;
        if (r < ROWS_PER_BLOCK) {
            s_c[r][0][k] = stm[NNZ + (row0 + r) * NNZ_PER + k];
            s_v[r][k]    = vals[(row0 + r) * NNZ_PER + k];
        } else {
            int rr = r - ROWS_PER_BLOCK;
            s_c[rr][1][k] = nstm[NNZ + (row0 + rr) * NNZ_PER + k];
        }
    }
    __syncthreads();

    int wid  = tid >> 6;
    int lane = tid & 63;
    int row  = row0 + wid;

    const uint4* wb = (const uint4*)Wt;     // 64 uint4 per feature row

    float a0[8] = {0, 0, 0, 0, 0, 0, 0, 0};   // stm, features lane*8..lane*8+7
    float a1[8] = {0, 0, 0, 0, 0, 0, 0, 0};   // nstm

    // software-pipelined gather: next-k loads issue while current k accumulates
    uint4 w0 = wb[(size_t)s_c[wid][0][0] * 64 + lane];
    uint4 w1 = wb[(size_t)s_c[wid][1][0] * 64 + lane];
#pragma unroll
    for (int k = 0; k < NNZ_PER - 1; k++) {
        uint4 c0 = w0, c1 = w1;
        w0 = wb[(size_t)s_c[wid][0][k + 1] * 64 + lane];
        w1 = wb[(size_t)s_c[wid][1][k + 1] * 64 + lane];
        float v = s_v[wid][k];
        acc8(c0, v, a0);
        acc8(c1, v, a1);
    }
    {
        float v = s_v[wid][NNZ_PER - 1];
        acc8(w0, v, a0);
        acc8(w1, v, a1);
    }

    int ob = lane * 8;

    // folded fft contraction for rows < MODV (only these rows receive the
    // mod-640 segment_sum contribution in the reference)
    if (row < MODV) {
        const float* H0 = H + (size_t)row * MODV;                 // stm side
        const float* H1 = H0 + (size_t)MODV * MODV;               // nstm side
        const float* wp = Wfft_t + ob;
        for (int cc = 0; cc < MODV; cc += 4) {
#pragma unroll
            for (int u = 0; u < 4; u++) {
                float h0 = H0[cc + u];                            // wave-uniform
                float h1 = H1[cc + u];
                const float4* wr = (const float4*)(wp + (size_t)(cc + u) * FT_OUT);
                float4 wa = wr[0];
                float4 wbv = wr[1];
                fma8(h0, wa, wbv, a0);
                fma8(h1, wa, wbv, a1);
            }
        }
    }

    float bft[8], bff[8], wo0[8], wo1[8];
    *(float4*)&bft[0] = ((const float4*)(b_ft + ob))[0];
    *(float4*)&bft[4] = ((const float4*)(b_ft + ob))[1];
    *(float4*)&bff[0] = ((const float4*)(b_fft + ob))[0];
    *(float4*)&bff[4] = ((const float4*)(b_fft + ob))[1];
    *(float4*)&wo0[0] = ((const float4*)(W_out + ob))[0];
    *(float4*)&wo0[4] = ((const float4*)(W_out + ob))[1];
    *(float4*)&wo1[0] = ((const float4*)(W_out + FT_OUT + ob))[0];
    *(float4*)&wo1[4] = ((const float4*)(W_out + FT_OUT + ob))[1];

    float dot = 0.0f;
#pragma unroll
    for (int i = 0; i < 8; i++) {
        float h0 = clip01(a0[i] + bft[i] + bff[i]);
        float h1 = clip01(a1[i] + bft[i] + bff[i]);
        dot += h0 * wo0[i] + h1 * wo1[i];
    }

#pragma unroll
    for (int off = 32; off > 0; off >>= 1)
        dot += __shfl_down(dot, off, 64);

    if (lane == 0)
        out[row] = 1.0f / (1.0f + expf(-(dot + b_out[0])));
}

extern "C" void kernel_launch(void* const* d_in, const int* in_sizes, int n_in,
                              void* d_out, int out_size, void* d_ws, size_t ws_size,
                              hipStream_t stream) {
    const int*   stm   = (const int*)d_in[0];
    const int*   nstm  = (const int*)d_in[1];
    const float* vals  = (const float*)d_in[2];
    // d_in[3]: size scalar (compile-time B_SZ)
    const float* W_ft  = (const float*)d_in[4];
    const float* b_ft  = (const float*)d_in[5];
    const float* W_fft = (const float*)d_in[6];
    const float* b_fft = (const float*)d_in[7];
    const float* W_out = (const float*)d_in[8];
    const float* b_out = (const float*)d_in[9];
    float* out = (float*)d_out;

    unsigned short* Wt_bf = (unsigned short*)d_ws;                  // F_BIG*FT_OUT ushort
    float* Wfft_t  = (float*)(Wt_bf + (size_t)F_BIG * FT_OUT);      // MODV*FT_OUT
    float* H       = Wfft_t + (size_t)MODV * FT_OUT;                // 2*MODV*MODV

    (void)hipMemsetAsync(H, 0, (size_t)2 * MODV * MODV * sizeof(float), stream);

    prep_kernel<<<PREP_GRID, 256, 0, stream>>>(W_ft, W_fft, stm, nstm, vals,
                                               Wt_bf, Wfft_t, H);
    main_kernel<<<B_SZ / ROWS_PER_BLOCK, 256, 0, stream>>>(
        stm, nstm, vals, Wt_bf, b_ft, b_fft, H, Wfft_t, W_out, b_out, out);
}